// Round 1
// baseline (2324.362 us; speedup 1.0000x reference)
//
#include <hip/hip_runtime.h>
#include <stdint.h>

#define LN_EPS 1e-5f

typedef short bf16x8 __attribute__((ext_vector_type(8)));
typedef short bf16x4 __attribute__((ext_vector_type(4)));
typedef float f32x4 __attribute__((ext_vector_type(4)));

__device__ __forceinline__ float bflo(uint32_t u){ return __uint_as_float(u << 16); }
__device__ __forceinline__ float bfhi(uint32_t u){ return __uint_as_float(u & 0xffff0000u); }
__device__ __forceinline__ uint16_t f2b(float f){
    uint32_t u = __float_as_uint(f);
    u += 0x7fffu + ((u >> 16) & 1u);
    return (uint16_t)(u >> 16);
}

// ---------------- convert f32 -> bf16 ----------------
__global__ void cvt_kernel(const float* __restrict__ src, uint16_t* __restrict__ dst, int n){
    int i = blockIdx.x * blockDim.x + threadIdx.x;
    int stride = gridDim.x * blockDim.x;
    for (; i < n; i += stride) dst[i] = f2b(src[i]);
}

// ---------------- init: zero loss accum, sum lengths ----------------
__global__ void init_kernel(const int* __restrict__ length, float* __restrict__ scal){
    if (threadIdx.x == 0 && blockIdx.x == 0){
        int s = 0;
        for (int i = 0; i < 32; i++) s += length[i];
        scal[0] = 0.f;
        scal[1] = (float)s;
    }
}

// ---------------- embedding + LN layer0 ----------------
__global__ __launch_bounds__(256) void embed_ln_kernel(
    const int* __restrict__ sent, const float* __restrict__ wordvec,
    const float* __restrict__ gamma, const float* __restrict__ beta,
    float* __restrict__ hn_f, uint16_t* __restrict__ hn_h)
{
    const int blk = blockIdx.x;          // t*32 + b
    const int t = blk >> 5, b = blk & 31;
    const int tid = threadIdx.x;
    __shared__ float red[8];
    const int tok = sent[b * 64 + t];
    const float x = wordvec[(size_t)tok * 256 + tid];
    float v = x;
    for (int o = 32; o; o >>= 1) v += __shfl_down(v, o);
    if ((tid & 63) == 0) red[tid >> 6] = v;
    __syncthreads();
    const float m = (red[0] + red[1] + red[2] + red[3]) * (1.f / 256.f);
    const float d = x - m;
    float v2 = d * d;
    for (int o = 32; o; o >>= 1) v2 += __shfl_down(v2, o);
    if ((tid & 63) == 0) red[4 + (tid >> 6)] = v2;
    __syncthreads();
    const float var = (red[4] + red[5] + red[6] + red[7]) * (1.f / 256.f);
    const float hn = d * rsqrtf(var + LN_EPS) * gamma[tid] + beta[tid];
    const size_t off = (size_t)blk * 256 + tid;
    hn_f[off] = hn;
    hn_h[off] = f2b(hn);
}

// ---------------- MFMA GEMM: C[M,N] = A[M,256] * B[N,256]^T + bias ----------------
// A,B bf16 row-major (K contiguous). REMAP: output row m=t*32+b -> b*63+t (logits layout).
template <bool REMAP>
__global__ __launch_bounds__(256) void gemm_bt_kernel(
    const uint16_t* __restrict__ A, const uint16_t* __restrict__ B,
    const float* __restrict__ bias, float* __restrict__ C,
    int M, int N)
{
    __shared__ __align__(16) uint16_t As[128 * 72];
    __shared__ __align__(16) uint16_t Bs[128 * 72];
    const int tid = threadIdx.x;
    const int lane = tid & 63, w = tid >> 6;
    const int wr = w >> 1, wc = w & 1;
    const int m0 = blockIdx.x * 128, n0 = blockIdx.y * 128;
    const int lr = lane & 15;
    const int lk = (lane >> 4) * 4;
    const int srow = tid >> 3;         // 0..31
    const int scol = (tid & 7) * 8;    // 0..56

    f32x4 acc[4][4] = {};

    for (int k0 = 0; k0 < 256; k0 += 64){
        __syncthreads();
        for (int p = 0; p < 4; p++){
            const int row = p * 32 + srow;
            uint4 va = make_uint4(0u, 0u, 0u, 0u);
            const int gm = m0 + row;
            if (gm < M) va = *(const uint4*)(A + (size_t)gm * 256 + k0 + scol);
            *(uint4*)(As + row * 72 + scol) = va;
            const uint4 vb = *(const uint4*)(B + (size_t)(n0 + row) * 256 + k0 + scol);
            *(uint4*)(Bs + row * 72 + scol) = vb;
        }
        __syncthreads();
        for (int kk = 0; kk < 64; kk += 32){
            bf16x8 bfr[4];
            for (int ni = 0; ni < 4; ni++){
                const uint16_t* p = Bs + (wc * 64 + ni * 16 + lr) * 72 + kk + lk;
                bf16x4 lo = *(const bf16x4*)p;
                bf16x4 hi = *(const bf16x4*)(p + 16);
                bfr[ni] = (bf16x8){lo[0], lo[1], lo[2], lo[3], hi[0], hi[1], hi[2], hi[3]};
            }
            for (int mi = 0; mi < 4; mi++){
                const uint16_t* p = As + (wr * 64 + mi * 16 + lr) * 72 + kk + lk;
                bf16x4 lo = *(const bf16x4*)p;
                bf16x4 hi = *(const bf16x4*)(p + 16);
                bf16x8 afr = (bf16x8){lo[0], lo[1], lo[2], lo[3], hi[0], hi[1], hi[2], hi[3]};
                for (int ni = 0; ni < 4; ni++)
                    acc[mi][ni] = __builtin_amdgcn_mfma_f32_16x16x32_bf16(afr, bfr[ni], acc[mi][ni], 0, 0, 0);
            }
        }
    }
    for (int mi = 0; mi < 4; mi++){
        const int gr_base = m0 + wr * 64 + mi * 16 + (lane >> 4) * 4;
        for (int ni = 0; ni < 4; ni++){
            const int gc = n0 + wc * 64 + ni * 16 + lr;
            const float bv = bias[gc];
            for (int r = 0; r < 4; r++){
                const int gm = gr_base + r;
                if (gm < M){
                    const size_t orow = REMAP ? (size_t)((gm & 31) * 63 + (gm >> 5)) : (size_t)gm;
                    C[orow * (size_t)N + gc] = acc[mi][ni][r] + bv;
                }
            }
        }
    }
}

// ---------------- recurrence: 1 block per batch element ----------------
__device__ __forceinline__ float dot_bf16_row(const uint16_t* __restrict__ wrow,
                                              const float* __restrict__ hs)
{
    const uint4* wp = (const uint4*)wrow;
    const float4* hp = (const float4*)hs;
    float a0 = 0.f, a1 = 0.f, a2 = 0.f, a3 = 0.f;
    #pragma unroll 8
    for (int c = 0; c < 32; c++){
        const uint4 u = wp[c];
        const float4 ha = hp[2 * c], hb = hp[2 * c + 1];
        a0 = fmaf(bflo(u.x), ha.x, a0); a0 = fmaf(bfhi(u.x), ha.y, a0);
        a1 = fmaf(bflo(u.y), ha.z, a1); a1 = fmaf(bfhi(u.y), ha.w, a1);
        a2 = fmaf(bflo(u.z), hb.x, a2); a2 = fmaf(bfhi(u.z), hb.y, a2);
        a3 = fmaf(bflo(u.w), hb.z, a3); a3 = fmaf(bfhi(u.w), hb.w, a3);
    }
    return (a0 + a1) + (a2 + a3);
}

__device__ __forceinline__ float sigm(float x){ return 1.f / (1.f + __expf(-x)); }

__global__ __launch_bounds__(768) void recurrence_kernel(
    const float* __restrict__ gi0, const float* __restrict__ hn0f,
    const uint16_t* __restrict__ whh0, const uint16_t* __restrict__ wih1,
    const uint16_t* __restrict__ whh1,
    const float* __restrict__ bhh0, const float* __restrict__ bih1,
    const float* __restrict__ bhh1,
    const float* __restrict__ g1, const float* __restrict__ be1,
    uint16_t* __restrict__ hidden_h)
{
    __shared__ __align__(16) float h0s[256], h1s[256], hn1s[256];
    __shared__ float ga[768], gb[768];
    __shared__ float red[24];
    const int tid = threadIdx.x;
    const int b = blockIdx.x;
    const int lane = tid & 63, wid = tid >> 6;
    if (tid < 256){ h0s[tid] = 0.f; h1s[tid] = 0.f; }
    __syncthreads();
    const uint16_t* w0r = whh0 + (size_t)tid * 256;
    const uint16_t* w1i = wih1 + (size_t)tid * 256;
    const uint16_t* w1h = whh1 + (size_t)tid * 256;
    const float bh0 = bhh0[tid], bi1 = bih1[tid], bh1 = bhh1[tid];
    const float gam = (tid < 256) ? g1[tid] : 0.f;
    const float bet = (tid < 256) ? be1[tid] : 0.f;

    for (int t = 0; t < 63; t++){
        const size_t row = (size_t)t * 32 + b;
        ga[tid] = gi0[row * 768 + tid];
        gb[tid] = bh0 + dot_bf16_row(w0r, h0s);
        __syncthreads();
        float hid = 0.f;
        if (tid < 256){
            const float r = sigm(ga[tid] + gb[tid]);
            const float z = sigm(ga[256 + tid] + gb[256 + tid]);
            const float n = tanhf(ga[512 + tid] + r * gb[512 + tid]);
            const float h0n = (1.f - z) * n + z * h0s[tid];
            hid = h0n + hn0f[row * 256 + tid];
            h0s[tid] = h0n;
        }
        float v = hid;
        for (int o = 32; o; o >>= 1) v += __shfl_down(v, o);
        if (lane == 0) red[wid] = v;
        __syncthreads();
        const float mean = (red[0] + red[1] + red[2] + red[3]) * (1.f / 256.f);
        const float d = hid - mean;
        float v2 = (tid < 256) ? d * d : 0.f;
        for (int o = 32; o; o >>= 1) v2 += __shfl_down(v2, o);
        if (lane == 0) red[12 + wid] = v2;
        __syncthreads();
        const float var = (red[12] + red[13] + red[14] + red[15]) * (1.f / 256.f);
        if (tid < 256) hn1s[tid] = d * rsqrtf(var + LN_EPS) * gam + bet;
        __syncthreads();
        ga[tid] = bi1 + dot_bf16_row(w1i, hn1s);
        gb[tid] = bh1 + dot_bf16_row(w1h, h1s);
        __syncthreads();
        if (tid < 256){
            const float r = sigm(ga[tid] + gb[tid]);
            const float z = sigm(ga[256 + tid] + gb[256 + tid]);
            const float n = tanhf(ga[512 + tid] + r * gb[512 + tid]);
            const float h1n = (1.f - z) * n + z * h1s[tid];
            const float outv = h1n + hn1s[tid];
            h1s[tid] = h1n;
            hidden_h[row * 256 + tid] = f2b(outv);
        }
        __syncthreads();
    }
}

// ---------------- CE / logsumexp over logits rows ----------------
__global__ __launch_bounds__(256) void ce_kernel(
    const float* __restrict__ logits, const int* __restrict__ sent,
    float* __restrict__ scal)
{
    const int orow = blockIdx.x;           // b*63 + t
    const int b = orow / 63, t = orow % 63;
    const float* row = logits + (size_t)orow * 32000;
    const int tid = threadIdx.x;
    const int lane = tid & 63, wid = tid >> 6;
    float m = -INFINITY, s = 0.f;
    const float4* r4 = (const float4*)row;
    for (int i = tid; i < 8000; i += 256){
        const float4 vv = r4[i];
        const float x[4] = {vv.x, vv.y, vv.z, vv.w};
        for (int j = 0; j < 4; j++){
            const float nm = fmaxf(m, x[j]);
            s = s * __expf(m - nm) + __expf(x[j] - nm);
            m = nm;
        }
    }
    for (int o = 32; o; o >>= 1){
        const float mo = __shfl_down(m, o);
        const float so = __shfl_down(s, o);
        const float nm = fmaxf(m, mo);
        s = s * __expf(m - nm) + so * __expf(mo - nm);
        m = nm;
    }
    __shared__ float rm[4], rs_[4];
    if (lane == 0){ rm[wid] = m; rs_[wid] = s; }
    __syncthreads();
    if (tid == 0){
        float M2 = rm[0], S2 = rs_[0];
        for (int i = 1; i < 4; i++){
            const float nm = fmaxf(M2, rm[i]);
            S2 = S2 * __expf(M2 - nm) + rs_[i] * __expf(rm[i] - nm);
            M2 = nm;
        }
        const int tgt = sent[b * 64 + t + 1];
        const float lse = M2 + logf(S2);
        const float ce = lse - row[tgt];
        if (tgt != 0) atomicAdd(scal, ce);
    }
}

__global__ void finalize_kernel(const float* __restrict__ scal, float* __restrict__ out){
    if (threadIdx.x == 0 && blockIdx.x == 0) out[0] = scal[0] / scal[1];
}

extern "C" void kernel_launch(void* const* d_in, const int* in_sizes, int n_in,
                              void* d_out, int out_size, void* d_ws, size_t ws_size,
                              hipStream_t stream)
{
    const int*   sent    = (const int*)  d_in[0];
    const int*   length  = (const int*)  d_in[1];
    const float* wordvec = (const float*)d_in[2];
    const float* W_ih    = (const float*)d_in[3];
    const float* W_hh    = (const float*)d_in[4];
    const float* b_ih    = (const float*)d_in[5];
    const float* b_hh    = (const float*)d_in[6];
    const float* ln_g    = (const float*)d_in[7];
    const float* ln_b    = (const float*)d_in[8];
    const float* lin_w   = (const float*)d_in[9];
    const float* lin_b   = (const float*)d_in[10];
    float* out = (float*)d_out;

    char* ws = (char*)d_ws;
    size_t off = 0;
    auto alloc = [&](size_t bytes) -> char* {
        char* p = ws + off;
        off += (bytes + 255) & ~(size_t)255;
        return p;
    };
    uint16_t* wih_h  = (uint16_t*)alloc((size_t)2 * 768 * 256 * 2);
    uint16_t* whh_h  = (uint16_t*)alloc((size_t)2 * 768 * 256 * 2);
    uint16_t* linw_h = (uint16_t*)alloc((size_t)32000 * 256 * 2);
    float*    hn0f   = (float*)   alloc((size_t)2016 * 256 * 4);
    uint16_t* hn0h   = (uint16_t*)alloc((size_t)2016 * 256 * 2);
    float*    gi0    = (float*)   alloc((size_t)2016 * 768 * 4);
    uint16_t* hidh   = (uint16_t*)alloc((size_t)2016 * 256 * 2);
    float*    scal   = (float*)   alloc(256);

    hipLaunchKernelGGL(cvt_kernel, dim3(512), dim3(256), 0, stream, W_ih, wih_h, 2 * 768 * 256);
    hipLaunchKernelGGL(cvt_kernel, dim3(512), dim3(256), 0, stream, W_hh, whh_h, 2 * 768 * 256);
    hipLaunchKernelGGL(cvt_kernel, dim3(2048), dim3(256), 0, stream, lin_w, linw_h, 32000 * 256);
    hipLaunchKernelGGL(init_kernel, dim3(1), dim3(1), 0, stream, length, scal);
    hipLaunchKernelGGL(embed_ln_kernel, dim3(2016), dim3(256), 0, stream,
                       sent, wordvec, ln_g, ln_b, hn0f, hn0h);
    hipLaunchKernelGGL(gemm_bt_kernel<false>, dim3(16, 6), dim3(256), 0, stream,
                       hn0h, wih_h, b_ih, gi0, 2016, 768);
    hipLaunchKernelGGL(recurrence_kernel, dim3(32), dim3(768), 0, stream,
                       gi0, hn0f, whh_h, wih_h + 768 * 256, whh_h + 768 * 256,
                       b_hh, b_ih + 768, b_hh + 768, ln_g + 256, ln_b + 256, hidh);
    hipLaunchKernelGGL(gemm_bt_kernel<true>, dim3(16, 250), dim3(256), 0, stream,
                       hidh, linw_h, lin_b, out + 1, 2016, 32000);
    hipLaunchKernelGGL(ce_kernel, dim3(2016), dim3(256), 0, stream, out + 1, sent, scal);
    hipLaunchKernelGGL(finalize_kernel, dim3(1), dim3(1), 0, stream, scal, out);
}

// Round 2
// 991.241 us; speedup vs baseline: 2.3449x; 2.3449x over previous
//
#include <hip/hip_runtime.h>
#include <stdint.h>

#define LN_EPS 1e-5f

typedef short bf16x8 __attribute__((ext_vector_type(8)));
typedef short bf16x4 __attribute__((ext_vector_type(4)));
typedef float f32x4 __attribute__((ext_vector_type(4)));

__device__ __forceinline__ float b2f(uint16_t v){ return __uint_as_float(((uint32_t)v) << 16); }
__device__ __forceinline__ uint16_t f2b(float f){
    uint32_t u = __float_as_uint(f);
    u += 0x7fffu + ((u >> 16) & 1u);
    return (uint16_t)(u >> 16);
}
__device__ __forceinline__ float sigm(float x){ return 1.f / (1.f + __expf(-x)); }
__device__ __forceinline__ float wred(float v){
    for (int o = 32; o; o >>= 1) v += __shfl_xor(v, o);
    return v;
}
__device__ __forceinline__ void waitflag(int* f){
    while (__hip_atomic_load(f, __ATOMIC_ACQUIRE, __HIP_MEMORY_SCOPE_AGENT) == 0)
        __builtin_amdgcn_s_sleep(1);
}
__device__ __forceinline__ bf16x8 mk8(bf16x4 lo, bf16x4 hi){
    return (bf16x8){lo[0], lo[1], lo[2], lo[3], hi[0], hi[1], hi[2], hi[3]};
}

// ---------------- convert f32 -> bf16 ----------------
__global__ void cvt_kernel(const float* __restrict__ src, uint16_t* __restrict__ dst, int n){
    int i = blockIdx.x * blockDim.x + threadIdx.x;
    int stride = gridDim.x * blockDim.x;
    for (; i < n; i += stride) dst[i] = f2b(src[i]);
}

// ---------------- init: zero loss accum, sum lengths ----------------
__global__ void init_kernel(const int* __restrict__ length, float* __restrict__ scal){
    if (threadIdx.x == 0 && blockIdx.x == 0){
        int s = 0;
        for (int i = 0; i < 32; i++) s += length[i];
        scal[0] = 0.f;
        scal[1] = (float)s;
    }
}

// ---------------- embedding + LN layer0 ----------------
__global__ __launch_bounds__(256) void embed_ln_kernel(
    const int* __restrict__ sent, const float* __restrict__ wordvec,
    const float* __restrict__ gamma, const float* __restrict__ beta,
    float* __restrict__ hn_f, uint16_t* __restrict__ hn_h)
{
    const int blk = blockIdx.x;          // t*32 + b
    const int t = blk >> 5, b = blk & 31;
    const int tid = threadIdx.x;
    __shared__ float red[8];
    const int tok = sent[b * 64 + t];
    const float x = wordvec[(size_t)tok * 256 + tid];
    float v = x;
    for (int o = 32; o; o >>= 1) v += __shfl_down(v, o);
    if ((tid & 63) == 0) red[tid >> 6] = v;
    __syncthreads();
    const float m = (red[0] + red[1] + red[2] + red[3]) * (1.f / 256.f);
    const float d = x - m;
    float v2 = d * d;
    for (int o = 32; o; o >>= 1) v2 += __shfl_down(v2, o);
    if ((tid & 63) == 0) red[4 + (tid >> 6)] = v2;
    __syncthreads();
    const float var = (red[4] + red[5] + red[6] + red[7]) * (1.f / 256.f);
    const float hn = d * rsqrtf(var + LN_EPS) * gamma[tid] + beta[tid];
    const size_t off = (size_t)blk * 256 + tid;
    hn_f[off] = hn;
    hn_h[off] = f2b(hn);
}

// ---------------- MFMA GEMM: C[M,N] = A[M,256] * B[N,256]^T + bias ----------------
template <bool REMAP>
__global__ __launch_bounds__(256) void gemm_bt_kernel(
    const uint16_t* __restrict__ A, const uint16_t* __restrict__ B,
    const float* __restrict__ bias, float* __restrict__ C,
    int M, int N)
{
    __shared__ __align__(16) uint16_t As[128 * 72];
    __shared__ __align__(16) uint16_t Bs[128 * 72];
    const int tid = threadIdx.x;
    const int lane = tid & 63, w = tid >> 6;
    const int wr = w >> 1, wc = w & 1;
    const int m0 = blockIdx.x * 128, n0 = blockIdx.y * 128;
    const int lr = lane & 15;
    const int lk = (lane >> 4) * 4;
    const int srow = tid >> 3;         // 0..31
    const int scol = (tid & 7) * 8;    // 0..56

    f32x4 acc[4][4] = {};

    for (int k0 = 0; k0 < 256; k0 += 64){
        __syncthreads();
        for (int p = 0; p < 4; p++){
            const int row = p * 32 + srow;
            uint4 va = make_uint4(0u, 0u, 0u, 0u);
            const int gm = m0 + row;
            if (gm < M) va = *(const uint4*)(A + (size_t)gm * 256 + k0 + scol);
            *(uint4*)(As + row * 72 + scol) = va;
            const uint4 vb = *(const uint4*)(B + (size_t)(n0 + row) * 256 + k0 + scol);
            *(uint4*)(Bs + row * 72 + scol) = vb;
        }
        __syncthreads();
        for (int kk = 0; kk < 64; kk += 32){
            bf16x8 bfr[4];
            for (int ni = 0; ni < 4; ni++){
                const uint16_t* p = Bs + (wc * 64 + ni * 16 + lr) * 72 + kk + lk;
                bfr[ni] = mk8(*(const bf16x4*)p, *(const bf16x4*)(p + 16));
            }
            for (int mi = 0; mi < 4; mi++){
                const uint16_t* p = As + (wr * 64 + mi * 16 + lr) * 72 + kk + lk;
                bf16x8 afr = mk8(*(const bf16x4*)p, *(const bf16x4*)(p + 16));
                for (int ni = 0; ni < 4; ni++)
                    acc[mi][ni] = __builtin_amdgcn_mfma_f32_16x16x32_bf16(afr, bfr[ni], acc[mi][ni], 0, 0, 0);
            }
        }
    }
    for (int mi = 0; mi < 4; mi++){
        const int gr_base = m0 + wr * 64 + mi * 16 + (lane >> 4) * 4;
        for (int ni = 0; ni < 4; ni++){
            const int gc = n0 + wc * 64 + ni * 16 + lr;
            const float bv = bias[gc];
            for (int r = 0; r < 4; r++){
                const int gm = gr_base + r;
                if (gm < M){
                    const size_t orow = REMAP ? (size_t)((gm & 31) * 63 + (gm >> 5)) : (size_t)gm;
                    C[orow * (size_t)N + gc] = acc[mi][ni][r] + bv;
                }
            }
        }
    }
}

// ---------------- 3-stage pipelined recurrence ----------------
// grid = 6 blocks: group g = bid/3 (16 batches), role = bid%3.
// role 0 (A): layer0 GRU chain + LN -> hn1buf[t], flagA
// role 1 (B): ga1[t] = Wih1 @ hn1[t] -> ga1buf, flagB
// role 2 (C): gb1 = Whh1 @ h1 chain + elementwise -> hidh
__global__ __launch_bounds__(512) void pipeline_kernel(
    const uint16_t* __restrict__ whh0, const uint16_t* __restrict__ wih1,
    const uint16_t* __restrict__ whh1,
    const float* __restrict__ gi0, const float* __restrict__ hn0f,
    const float* __restrict__ bhh0, const float* __restrict__ bih1,
    const float* __restrict__ bhh1,
    const float* __restrict__ g1, const float* __restrict__ be1,
    uint16_t* __restrict__ hn1buf, float* __restrict__ ga1buf,
    uint16_t* __restrict__ hidh, int* __restrict__ flags)
{
    const int bid = blockIdx.x;
    const int g = bid / 3, role = bid - g * 3;
    const int tid = threadIdx.x;
    const int lane = tid & 63, w = tid >> 6;
    const int lr = lane & 15, lk4 = (lane >> 4) * 4;
    __shared__ __align__(16) char smem[51712];
    // carve: hf f32[16][256] @0 (16384) | hb u16[16][264] @16384 (8448)
    //        gb u16[768][17] @24832 (26112) | red f32[16][8] @50944 (512)

    if (role == 0){
        float*    h0f = (float*)smem;
        uint16_t* h0b = (uint16_t*)(smem + 16384);
        uint16_t* gb  = (uint16_t*)(smem + 24832);
        float*    red = (float*)(smem + 50944);
        for (int i = tid; i < 4096; i += 512) h0f[i] = 0.f;
        for (int i = tid; i < 4224; i += 512) h0b[i] = 0;
        const int u = tid & 255, bl0 = tid >> 8;
        const float bhr = bhh0[u], bhz = bhh0[256 + u], bhn = bhh0[512 + u];
        const float gam = g1[u], bet = be1[u];
        __syncthreads();
        for (int t = 0; t < 63; t++){
            bf16x8 hfrag[8];
            #pragma unroll
            for (int kc = 0; kc < 8; kc++){
                const uint16_t* hp = h0b + lr * 264 + kc * 32 + lk4;
                hfrag[kc] = mk8(*(const bf16x4*)hp, *(const bf16x4*)(hp + 16));
            }
            for (int i = 0; i < 6; i++){
                const int rt = w * 6 + i;
                f32x4 acc = {0.f, 0.f, 0.f, 0.f};
                const uint16_t* wp = whh0 + (size_t)(rt * 16 + lr) * 256 + lk4;
                #pragma unroll
                for (int kc = 0; kc < 8; kc++){
                    bf16x8 afr = mk8(*(const bf16x4*)(wp + kc * 32), *(const bf16x4*)(wp + kc * 32 + 16));
                    acc = __builtin_amdgcn_mfma_f32_16x16x32_bf16(afr, hfrag[kc], acc, 0, 0, 0);
                }
                const int rbase = rt * 16 + (lane >> 4) * 4;
                #pragma unroll
                for (int j = 0; j < 4; j++) gb[(rbase + j) * 17 + lr] = f2b(acc[j]);
            }
            __syncthreads();
            float hv[8];
            #pragma unroll
            for (int p = 0; p < 8; p++){
                const int b = 2 * p + bl0;
                const size_t rowg = (size_t)t * 32 + g * 16 + b;
                const float gar = gi0[rowg * 768 + u];
                const float gaz = gi0[rowg * 768 + 256 + u];
                const float gan = gi0[rowg * 768 + 512 + u];
                const float gbr = b2f(gb[u * 17 + b]);
                const float gbz = b2f(gb[(256 + u) * 17 + b]);
                const float gbn = b2f(gb[(512 + u) * 17 + b]);
                const float r = sigm(gar + gbr + bhr);
                const float z = sigm(gaz + gbz + bhz);
                const float n = tanhf(gan + r * (gbn + bhn));
                const float h0n = (1.f - z) * n + z * h0f[b * 256 + u];
                h0f[b * 256 + u] = h0n;
                h0b[b * 264 + u] = f2b(h0n);
                const float hidv = h0n + hn0f[rowg * 256 + u];
                hv[p] = hidv;
                const float s1 = wred(hidv), s2 = wred(hidv * hidv);
                if (lane == 0){ red[b * 8 + (w & 3)] = s1; red[b * 8 + 4 + (w & 3)] = s2; }
            }
            __syncthreads();
            #pragma unroll
            for (int p = 0; p < 8; p++){
                const int b = 2 * p + bl0;
                const size_t rowg = (size_t)t * 32 + g * 16 + b;
                const float m  = (red[b * 8] + red[b * 8 + 1] + red[b * 8 + 2] + red[b * 8 + 3]) * (1.f / 256.f);
                const float e2 = (red[b * 8 + 4] + red[b * 8 + 5] + red[b * 8 + 6] + red[b * 8 + 7]) * (1.f / 256.f);
                const float rs = rsqrtf(fmaxf(e2 - m * m, 0.f) + LN_EPS);
                const float hn1 = (hv[p] - m) * rs * gam + bet;
                hn1buf[rowg * 256 + u] = f2b(hn1);
            }
            __syncthreads();   // drains all waves' global writes (vmcnt 0 before barrier)
            if (tid == 0){
                __threadfence();
                __hip_atomic_store(&flags[g * 64 + t], 1, __ATOMIC_RELEASE, __HIP_MEMORY_SCOPE_AGENT);
            }
        }
    } else if (role == 1){
        for (int t = 0; t < 63; t++){
            if (tid == 0) waitflag(&flags[g * 64 + t]);
            __syncthreads();
            bf16x8 hfrag[8];
            const uint16_t* hp0 = hn1buf + ((size_t)t * 32 + g * 16 + lr) * 256 + lk4;
            #pragma unroll
            for (int kc = 0; kc < 8; kc++)
                hfrag[kc] = mk8(*(const bf16x4*)(hp0 + kc * 32), *(const bf16x4*)(hp0 + kc * 32 + 16));
            for (int i = 0; i < 6; i++){
                const int rt = w * 6 + i;
                f32x4 acc = {0.f, 0.f, 0.f, 0.f};
                const uint16_t* wp = wih1 + (size_t)(rt * 16 + lr) * 256 + lk4;
                #pragma unroll
                for (int kc = 0; kc < 8; kc++){
                    bf16x8 afr = mk8(*(const bf16x4*)(wp + kc * 32), *(const bf16x4*)(wp + kc * 32 + 16));
                    acc = __builtin_amdgcn_mfma_f32_16x16x32_bf16(afr, hfrag[kc], acc, 0, 0, 0);
                }
                const int rbase = rt * 16 + (lane >> 4) * 4;
                float* gp = ga1buf + ((size_t)(t * 2 + g) * 16 + lr) * 768 + rbase;
                *(float4*)gp = make_float4(acc[0], acc[1], acc[2], acc[3]);
            }
            __syncthreads();
            if (tid == 0){
                __threadfence();
                __hip_atomic_store(&flags[128 + g * 64 + t], 1, __ATOMIC_RELEASE, __HIP_MEMORY_SCOPE_AGENT);
            }
        }
    } else {
        float*    h1f = (float*)smem;
        uint16_t* h1b = (uint16_t*)(smem + 16384);
        uint16_t* gb  = (uint16_t*)(smem + 24832);
        for (int i = tid; i < 4096; i += 512) h1f[i] = 0.f;
        for (int i = tid; i < 4224; i += 512) h1b[i] = 0;
        const int u = tid & 255, bl0 = tid >> 8;
        const float bir = bih1[u], biz = bih1[256 + u], bin = bih1[512 + u];
        const float bhr = bhh1[u], bhz = bhh1[256 + u], bhn = bhh1[512 + u];
        __syncthreads();
        for (int t = 0; t < 63; t++){
            bf16x8 hfrag[8];
            #pragma unroll
            for (int kc = 0; kc < 8; kc++){
                const uint16_t* hp = h1b + lr * 264 + kc * 32 + lk4;
                hfrag[kc] = mk8(*(const bf16x4*)hp, *(const bf16x4*)(hp + 16));
            }
            for (int i = 0; i < 6; i++){
                const int rt = w * 6 + i;
                f32x4 acc = {0.f, 0.f, 0.f, 0.f};
                const uint16_t* wp = whh1 + (size_t)(rt * 16 + lr) * 256 + lk4;
                #pragma unroll
                for (int kc = 0; kc < 8; kc++){
                    bf16x8 afr = mk8(*(const bf16x4*)(wp + kc * 32), *(const bf16x4*)(wp + kc * 32 + 16));
                    acc = __builtin_amdgcn_mfma_f32_16x16x32_bf16(afr, hfrag[kc], acc, 0, 0, 0);
                }
                const int rbase = rt * 16 + (lane >> 4) * 4;
                #pragma unroll
                for (int j = 0; j < 4; j++) gb[(rbase + j) * 17 + lr] = f2b(acc[j]);
            }
            if (tid == 0) waitflag(&flags[128 + g * 64 + t]);
            __syncthreads();
            #pragma unroll
            for (int p = 0; p < 8; p++){
                const int b = 2 * p + bl0;
                const size_t rowg = (size_t)t * 32 + g * 16 + b;
                const size_t gbase = ((size_t)(t * 2 + g) * 16 + b) * 768;
                const float gar = ga1buf[gbase + u] + bir;
                const float gaz = ga1buf[gbase + 256 + u] + biz;
                const float gan = ga1buf[gbase + 512 + u] + bin;
                const float gbr = b2f(gb[u * 17 + b]) + bhr;
                const float gbz = b2f(gb[(256 + u) * 17 + b]) + bhz;
                const float gbn = b2f(gb[(512 + u) * 17 + b]) + bhn;
                const float r = sigm(gar + gbr);
                const float z = sigm(gaz + gbz);
                const float n = tanhf(gan + r * gbn);
                const float h1n = (1.f - z) * n + z * h1f[b * 256 + u];
                h1f[b * 256 + u] = h1n;
                h1b[b * 264 + u] = f2b(h1n);
                const float outv = h1n + b2f(hn1buf[rowg * 256 + u]);
                hidh[rowg * 256 + u] = f2b(outv);
            }
            __syncthreads();
        }
    }
}

// ---------------- CE / logsumexp over logits rows ----------------
__global__ __launch_bounds__(256) void ce_kernel(
    const float* __restrict__ logits, const int* __restrict__ sent,
    float* __restrict__ scal)
{
    const int orow = blockIdx.x;           // b*63 + t
    const int b = orow / 63, t = orow % 63;
    const float* row = logits + (size_t)orow * 32000;
    const int tid = threadIdx.x;
    const int lane = tid & 63, wid = tid >> 6;
    float m = -INFINITY, s = 0.f;
    const float4* r4 = (const float4*)row;
    for (int i = tid; i < 8000; i += 256){
        const float4 vv = r4[i];
        const float x[4] = {vv.x, vv.y, vv.z, vv.w};
        for (int j = 0; j < 4; j++){
            const float nm = fmaxf(m, x[j]);
            s = s * __expf(m - nm) + __expf(x[j] - nm);
            m = nm;
        }
    }
    for (int o = 32; o; o >>= 1){
        const float mo = __shfl_down(m, o);
        const float so = __shfl_down(s, o);
        const float nm = fmaxf(m, mo);
        s = s * __expf(m - nm) + so * __expf(mo - nm);
        m = nm;
    }
    __shared__ float rm[4], rs_[4];
    if (lane == 0){ rm[wid] = m; rs_[wid] = s; }
    __syncthreads();
    if (tid == 0){
        float M2 = rm[0], S2 = rs_[0];
        for (int i = 1; i < 4; i++){
            const float nm = fmaxf(M2, rm[i]);
            S2 = S2 * __expf(M2 - nm) + rs_[i] * __expf(rm[i] - nm);
            M2 = nm;
        }
        const int tgt = sent[b * 64 + t + 1];
        const float lse = M2 + logf(S2);
        const float ce = lse - row[tgt];
        if (tgt != 0) atomicAdd(scal, ce);
    }
}

__global__ void finalize_kernel(const float* __restrict__ scal, float* __restrict__ out){
    if (threadIdx.x == 0 && blockIdx.x == 0) out[0] = scal[0] / scal[1];
}

extern "C" void kernel_launch(void* const* d_in, const int* in_sizes, int n_in,
                              void* d_out, int out_size, void* d_ws, size_t ws_size,
                              hipStream_t stream)
{
    const int*   sent    = (const int*)  d_in[0];
    const int*   length  = (const int*)  d_in[1];
    const float* wordvec = (const float*)d_in[2];
    const float* W_ih    = (const float*)d_in[3];
    const float* W_hh    = (const float*)d_in[4];
    const float* b_ih    = (const float*)d_in[5];
    const float* b_hh    = (const float*)d_in[6];
    const float* ln_g    = (const float*)d_in[7];
    const float* ln_b    = (const float*)d_in[8];
    const float* lin_w   = (const float*)d_in[9];
    const float* lin_b   = (const float*)d_in[10];
    float* out = (float*)d_out;

    char* ws = (char*)d_ws;
    size_t off = 0;
    auto alloc = [&](size_t bytes) -> char* {
        char* p = ws + off;
        off += (bytes + 255) & ~(size_t)255;
        return p;
    };
    uint16_t* wih_h  = (uint16_t*)alloc((size_t)2 * 768 * 256 * 2);
    uint16_t* whh_h  = (uint16_t*)alloc((size_t)2 * 768 * 256 * 2);
    uint16_t* linw_h = (uint16_t*)alloc((size_t)32000 * 256 * 2);
    float*    hn0f   = (float*)   alloc((size_t)2016 * 256 * 4);
    uint16_t* hn0h   = (uint16_t*)alloc((size_t)2016 * 256 * 2);
    float*    gi0    = (float*)   alloc((size_t)2016 * 768 * 4);
    uint16_t* hidh   = (uint16_t*)alloc((size_t)2016 * 256 * 2);
    float*    scal   = (float*)   alloc(256);
    uint16_t* hn1buf = (uint16_t*)alloc((size_t)63 * 32 * 256 * 2);
    float*    ga1buf = (float*)   alloc((size_t)63 * 2 * 16 * 768 * 4);
    int*      flags  = (int*)     alloc(1024);

    hipLaunchKernelGGL(cvt_kernel, dim3(512), dim3(256), 0, stream, W_ih, wih_h, 2 * 768 * 256);
    hipLaunchKernelGGL(cvt_kernel, dim3(512), dim3(256), 0, stream, W_hh, whh_h, 2 * 768 * 256);
    hipLaunchKernelGGL(cvt_kernel, dim3(2048), dim3(256), 0, stream, lin_w, linw_h, 32000 * 256);
    hipLaunchKernelGGL(init_kernel, dim3(1), dim3(1), 0, stream, length, scal);
    hipMemsetAsync(flags, 0, 1024, stream);
    hipLaunchKernelGGL(embed_ln_kernel, dim3(2016), dim3(256), 0, stream,
                       sent, wordvec, ln_g, ln_b, hn0f, hn0h);
    hipLaunchKernelGGL(gemm_bt_kernel<false>, dim3(16, 6), dim3(256), 0, stream,
                       hn0h, wih_h, b_ih, gi0, 2016, 768);

    {
        const uint16_t* whh0p = whh_h;
        const uint16_t* wih1p = wih_h + 768 * 256;
        const uint16_t* whh1p = whh_h + 768 * 256;
        const float* gi0p = gi0;
        const float* hn0fp = hn0f;
        const float* bhh0p = b_hh;
        const float* bih1p = b_ih + 768;
        const float* bhh1p = b_hh + 768;
        const float* g1p = ln_g + 256;
        const float* be1p = ln_b + 256;
        uint16_t* hn1p = hn1buf;
        float* ga1p = ga1buf;
        uint16_t* hidp = hidh;
        int* flagp = flags;
        void* kargs[] = {
            (void*)&whh0p, (void*)&wih1p, (void*)&whh1p,
            (void*)&gi0p, (void*)&hn0fp,
            (void*)&bhh0p, (void*)&bih1p, (void*)&bhh1p,
            (void*)&g1p, (void*)&be1p,
            (void*)&hn1p, (void*)&ga1p, (void*)&hidp, (void*)&flagp
        };
        hipLaunchCooperativeKernel((const void*)pipeline_kernel, dim3(6), dim3(512),
                                   kargs, 0, stream);
    }

    hipLaunchKernelGGL(gemm_bt_kernel<true>, dim3(16, 250), dim3(256), 0, stream,
                       hidh, linw_h, lin_b, out + 1, 2016, 32000);
    hipLaunchKernelGGL(ce_kernel, dim3(2016), dim3(256), 0, stream, out + 1, sent, scal);
    hipLaunchKernelGGL(finalize_kernel, dim3(1), dim3(1), 0, stream, scal, out);
}